// Round 1
// baseline (4375.863 us; speedup 1.0000x reference)
//
#include <hip/hip_runtime.h>
#include <hip/hip_bf16.h>
#include <cstdint>

// Problem constants (from reference)
constexpr int B    = 256;
constexpr int S    = 33;
constexpr int D    = 42;
constexpr int H    = 128;
constexpr int HFF  = 256;
constexpr int T    = 20;
constexpr int NSTEP = S - 1; // 32
// 1/sqrt(1 + 1e-5)
#define BN_SCALE 0.9999950000374997f

__device__ __forceinline__ float gelu_exact(float x) {
    return 0.5f * x * (1.0f + erff(x * 0.70710678118654752f));
}
__device__ __forceinline__ float bflo(uint32_t w) { return __uint_as_float(w << 16); }
__device__ __forceinline__ float bfhi(uint32_t w) { return __uint_as_float(w & 0xffff0000u); }
__device__ __forceinline__ uint16_t f2bf(float f) {
    uint32_t u = __float_as_uint(f);
    uint32_t r = (u + 0x7fffu + ((u >> 16) & 1u)) >> 16;
    return (uint16_t)r;
}

// ---------------------------------------------------------------------------
// K0: convert vf weights to bf16, packed in i-pairs so eval can do 4B loads:
//   dst[(i>>1)*(2*N) + j*2 + (i&1)] = bf16(src[i*N + j])
// ---------------------------------------------------------------------------
__global__ void pack_weights(const float* __restrict__ w0,
                             const float* __restrict__ w1,
                             const float* __restrict__ w2,
                             uint16_t* __restrict__ w0p,
                             uint16_t* __restrict__ w1p,
                             uint16_t* __restrict__ w2p) {
    int idx = blockIdx.x * 256 + threadIdx.x;
    if (idx < H * HFF) {
        int i = idx / HFF, j = idx % HFF;
        w0p[(i >> 1) * (2 * HFF) + j * 2 + (i & 1)] = f2bf(w0[idx]);
    }
    if (idx < HFF * HFF) {
        int i = idx / HFF, j = idx % HFF;
        int dst = (i >> 1) * (2 * HFF) + j * 2 + (i & 1);
        w1p[dst] = f2bf(w1[idx]);
        w2p[dst] = f2bf(w2[idx]);
    }
}

// ---------------------------------------------------------------------------
// K1: encoder (z0) + dxdt + dt.  One block per sample, 128 threads.
// ---------------------------------------------------------------------------
__global__ void prep_kernel(const float* __restrict__ path, const float* __restrict__ ts,
                            const float* __restrict__ ew1, const float* __restrict__ eb1,
                            const float* __restrict__ eg1, const float* __restrict__ ebe1,
                            const float* __restrict__ ew2, const float* __restrict__ eb2,
                            const float* __restrict__ eg2, const float* __restrict__ ebe2,
                            float* __restrict__ zbuf, float* __restrict__ dxdt,
                            float* __restrict__ dtb) {
    __shared__ float x0[D], hb[H];
    int b = blockIdx.x, tid = threadIdx.x;
    if (tid < D) x0[tid] = path[b * S * D + tid];
    __syncthreads();
    {
        float acc = eb1[tid];
        for (int d = 0; d < D; ++d) acc += x0[d] * ew1[d * H + tid];
        hb[tid] = gelu_exact(acc * (eg1[tid] * BN_SCALE) + ebe1[tid]);
    }
    __syncthreads();
    {
        float acc = eb2[tid];
        for (int i = 0; i < H; ++i) acc += hb[i] * ew2[i * H + tid];
        zbuf[b * H + tid] = acc * (eg2[tid] * BN_SCALE) + ebe2[tid];
    }
    for (int idx = tid; idx < NSTEP * D; idx += 128) {
        int s = idx / D, d = idx % D;
        float dtv = ts[s + 1] - ts[s];
        dxdt[(s * B + b) * D + d] =
            (path[b * S * D + (s + 1) * D + d] - path[b * S * D + s * D + d]) / dtv;
    }
    if (b == 0 && tid < NSTEP) dtb[tid] = ts[tid + 1] - ts[tid];
}

// ---------------------------------------------------------------------------
// K2 (per step s): A[b,e,h] = sum_d w3[e, h*D+d] * dxdt[s,b,d], stored bf16
// packed in e-pairs: Ab[b*32768 + (e>>1)*(2H) + h*2 + (e&1)].
// grid 256: (eh-chunk of 256) x (b-half of 128). Lane owns (e,h); w3 row in
// 42 VGPRs; dxdt row is wave-uniform -> scalar loads.
// ---------------------------------------------------------------------------
__global__ void a_step(const float* __restrict__ w3, const float* __restrict__ dxdt,
                       uint16_t* __restrict__ Ab, int s) {
    int tid = threadIdx.x;
    int ehc = blockIdx.x & 127, bh = blockIdx.x >> 7;
    int eh = ehc * 256 + tid;
    int e = eh >> 7, h = eh & 127;
    float wrow[D];
    const float* wp = w3 + e * (H * D) + h * D;
#pragma unroll
    for (int d = 0; d < D; ++d) wrow[d] = wp[d];
    int dstbase = (e >> 1) * (2 * H) + h * 2 + (e & 1);
    int b0 = bh * 128;
    for (int b = b0; b < b0 + 128; ++b) {
        const float* dx = dxdt + (size_t)(s * B + b) * D;
        float acc = 0.f;
#pragma unroll
        for (int d = 0; d < D; ++d) acc += wrow[d] * dx[d];
        Ab[(size_t)b * (HFF * H) + dstbase] = f2bf(acc);
    }
}

// ---------------------------------------------------------------------------
// K3 (per step s): one RK4 step for one sample per block (256 threads).
// Activations in LDS; bf16 packed weights from L2; A from LLC.
// ---------------------------------------------------------------------------
__global__ void __launch_bounds__(256) eval_step(
    const uint16_t* __restrict__ w0p, const uint16_t* __restrict__ w1p,
    const uint16_t* __restrict__ w2p,
    const float* __restrict__ vb0, const float* __restrict__ vg0, const float* __restrict__ vbe0,
    const float* __restrict__ vb1, const float* __restrict__ vg1, const float* __restrict__ vbe1,
    const float* __restrict__ vb2, const float* __restrict__ vg2, const float* __restrict__ vbe2,
    const float* __restrict__ b3, const uint16_t* __restrict__ Ab,
    const float* __restrict__ dxdt, const float* __restrict__ dtb,
    float* __restrict__ zbuf, int s) {
    __shared__ float dx[D], z[H], zz[H], ksum[H], kcur[H], bd3[H];
    __shared__ float y0[HFF], y1[HFF], y2[HFF];
    int b = blockIdx.x, tid = threadIdx.x;
    if (tid < D) dx[tid] = dxdt[(size_t)(s * B + b) * D + tid];
    if (tid < H) z[tid] = zbuf[b * H + tid];
    float hstep = dtb[s];
    float c0b = vb0[tid], c0g = vg0[tid] * BN_SCALE, c0e = vbe0[tid];
    float c1b = vb1[tid], c1g = vg1[tid] * BN_SCALE, c1e = vbe1[tid];
    float c2b = vb2[tid], c2g = vg2[tid] * BN_SCALE, c2e = vbe2[tid];
    __syncthreads();
    if (tid < H) {
        float acc = 0.f;
        const float* bp = b3 + tid * D;
#pragma unroll
        for (int d = 0; d < D; ++d) acc += bp[d] * dx[d];
        bd3[tid] = acc;
    }
    const uint32_t* W0 = (const uint32_t*)w0p;
    const uint32_t* W1 = (const uint32_t*)w1p;
    const uint32_t* W2 = (const uint32_t*)w2p;
    const uint32_t* A32 = (const uint32_t*)(Ab + (size_t)b * (HFF * H));
    const float cin[4] = {0.f, 0.5f, 0.5f, 1.f};
    const float wsm[4] = {1.f, 2.f, 2.f, 1.f};

    for (int r = 0; r < 4; ++r) {
        if (tid < H) zz[tid] = (r == 0) ? z[tid] : z[tid] + cin[r] * hstep * kcur[tid];
        __syncthreads();
        // L0: 128 -> 256
        {
            float acc = c0b;
#pragma unroll 8
            for (int i2 = 0; i2 < H / 2; ++i2) {
                uint32_t w = W0[i2 * HFF + tid];
                acc += zz[2 * i2] * bflo(w) + zz[2 * i2 + 1] * bfhi(w);
            }
            y0[tid] = gelu_exact(acc * c0g + c0e);
        }
        __syncthreads();
        // L1: 256 -> 256
        {
            float acc = c1b;
#pragma unroll 8
            for (int i2 = 0; i2 < HFF / 2; ++i2) {
                uint32_t w = W1[i2 * HFF + tid];
                acc += y0[2 * i2] * bflo(w) + y0[2 * i2 + 1] * bfhi(w);
            }
            y1[tid] = gelu_exact(acc * c1g + c1e);
        }
        __syncthreads();
        // L2: 256 -> 256
        {
            float acc = c2b;
#pragma unroll 8
            for (int i2 = 0; i2 < HFF / 2; ++i2) {
                uint32_t w = W2[i2 * HFF + tid];
                acc += y1[2 * i2] * bflo(w) + y1[2 * i2 + 1] * bfhi(w);
            }
            y2[tid] = gelu_exact(acc * c2g + c2e);
        }
        __syncthreads();
        // L3: g[h] = bd3[h] + sum_e y2[e] * A[e,h]
        if (tid < H) {
            float acc = bd3[tid];
#pragma unroll 8
            for (int e2 = 0; e2 < HFF / 2; ++e2) {
                uint32_t a2 = A32[e2 * H + tid];
                acc += y2[2 * e2] * bflo(a2) + y2[2 * e2 + 1] * bfhi(a2);
            }
            kcur[tid] = acc;
        }
        __syncthreads();
        if (tid < H) ksum[tid] = ((r == 0) ? 0.f : ksum[tid]) + wsm[r] * kcur[tid];
    }
    if (tid < H) zbuf[b * H + tid] = z[tid] + (hstep * (1.f / 6.f)) * ksum[tid];
}

// ---------------------------------------------------------------------------
// K4: attended = (zT@wv+bv)@wo+bo, then per-t decoder MLP + sigmoid.
// One block per sample, 128 threads.
// ---------------------------------------------------------------------------
__global__ void decoder_kernel(const float* __restrict__ zbuf,
                               const float* __restrict__ wv, const float* __restrict__ bv,
                               const float* __restrict__ wo, const float* __restrict__ bo,
                               const float* __restrict__ dw1, const float* __restrict__ db1,
                               const float* __restrict__ dw2, const float* __restrict__ db2,
                               const float* __restrict__ dw3, const float* __restrict__ db3,
                               float* __restrict__ out) {
    __shared__ float zl[H], v[H], att[H], h1[64], h2[32];
    int b = blockIdx.x, tid = threadIdx.x;
    zl[tid] = zbuf[b * H + tid];
    __syncthreads();
    {
        float acc = bv[tid];
        for (int i = 0; i < H; ++i) acc += zl[i] * wv[i * H + tid];
        v[tid] = acc;
    }
    __syncthreads();
    {
        float acc = bo[tid];
        for (int i = 0; i < H; ++i) acc += v[i] * wo[i * H + tid];
        att[tid] = acc;
    }
    __syncthreads();
    for (int t = 0; t < T; ++t) {
        if (tid < 64) {
            float acc = db1[t * 64 + tid];
            for (int i = 0; i < H; ++i) acc += att[i] * dw1[t * H * 64 + i * 64 + tid];
            h1[tid] = gelu_exact(acc);
        }
        __syncthreads();
        if (tid < 32) {
            float acc = db2[t * 32 + tid];
            for (int i = 0; i < 64; ++i) acc += h1[i] * dw2[t * 64 * 32 + i * 32 + tid];
            h2[tid] = gelu_exact(acc);
        }
        __syncthreads();
        if (tid == 0) {
            float acc = db3[t];
            for (int i = 0; i < 32; ++i) acc += h2[i] * dw3[t * 32 + i];
            out[b * T + t] = 1.f / (1.f + expf(-acc));
        }
        __syncthreads();
    }
}

// ---------------------------------------------------------------------------
extern "C" void kernel_launch(void* const* d_in, const int* in_sizes, int n_in,
                              void* d_out, int out_size, void* d_ws, size_t ws_size,
                              hipStream_t stream) {
    const float* path = (const float*)d_in[0];
    const float* ts   = (const float*)d_in[1];
    const float* ew1  = (const float*)d_in[2];
    const float* eb1  = (const float*)d_in[3];
    const float* eg1  = (const float*)d_in[4];
    const float* ebe1 = (const float*)d_in[5];
    const float* ew2  = (const float*)d_in[6];
    const float* eb2  = (const float*)d_in[7];
    const float* eg2  = (const float*)d_in[8];
    const float* ebe2 = (const float*)d_in[9];
    const float* vw0  = (const float*)d_in[10];
    const float* vb0  = (const float*)d_in[11];
    const float* vg0  = (const float*)d_in[12];
    const float* vbe0 = (const float*)d_in[13];
    const float* vw1  = (const float*)d_in[14];
    const float* vb1  = (const float*)d_in[15];
    const float* vg1  = (const float*)d_in[16];
    const float* vbe1 = (const float*)d_in[17];
    const float* vw2  = (const float*)d_in[18];
    const float* vb2  = (const float*)d_in[19];
    const float* vg2  = (const float*)d_in[20];
    const float* vbe2 = (const float*)d_in[21];
    const float* vw3  = (const float*)d_in[22];
    const float* vb3  = (const float*)d_in[23];
    const float* wv   = (const float*)d_in[24];
    const float* bv   = (const float*)d_in[25];
    const float* wo   = (const float*)d_in[26];
    const float* bo   = (const float*)d_in[27];
    const float* dw1  = (const float*)d_in[28];
    const float* db1  = (const float*)d_in[29];
    const float* dw2  = (const float*)d_in[30];
    const float* db2  = (const float*)d_in[31];
    const float* dw3  = (const float*)d_in[32];
    const float* db3  = (const float*)d_in[33];

    // workspace layout (~18.6 MB)
    char* ws = (char*)d_ws;
    uint16_t* Ab   = (uint16_t*)ws;                         // 256*32768*2 = 16,777,216
    float*    dxdt = (float*)(ws + 16777216);               // 32*256*42*4 = 1,376,256
    float*    dtb  = (float*)(ws + 16777216 + 1376256);     // 128 B
    float*    zbuf = (float*)(ws + 18153600);               // 256*128*4 = 131,072
    uint16_t* w0p  = (uint16_t*)(ws + 18284672);            // 65,536
    uint16_t* w1p  = (uint16_t*)(ws + 18350208);            // 131,072
    uint16_t* w2p  = (uint16_t*)(ws + 18481280);            // 131,072 -> end 18,612,352

    pack_weights<<<(HFF * HFF) / 256, 256, 0, stream>>>(vw0, vw1, vw2, w0p, w1p, w2p);
    prep_kernel<<<B, 128, 0, stream>>>(path, ts, ew1, eb1, eg1, ebe1,
                                       ew2, eb2, eg2, ebe2, zbuf, dxdt, dtb);
    for (int s = 0; s < NSTEP; ++s) {
        a_step<<<256, 256, 0, stream>>>(vw3, dxdt, Ab, s);
        eval_step<<<B, 256, 0, stream>>>(w0p, w1p, w2p,
                                         vb0, vg0, vbe0, vb1, vg1, vbe1, vb2, vg2, vbe2,
                                         vb3, Ab, dxdt, dtb, zbuf, s);
    }
    decoder_kernel<<<B, 128, 0, stream>>>(zbuf, wv, bv, wo, bo,
                                          dw1, db1, dw2, db2, dw3, db3, (float*)d_out);
}

// Round 2
// 1512.320 us; speedup vs baseline: 2.8935x; 2.8935x over previous
//
#include <hip/hip_runtime.h>
#include <cstdint>

constexpr int B    = 256;
constexpr int S    = 33;
constexpr int D    = 42;
constexpr int H    = 128;
constexpr int HFF  = 256;
constexpr int T    = 20;
constexpr int NSTEP = S - 1;        // 32
constexpr int DP   = D / 2;         // 21 f16 pairs along d
constexpr int QN   = (HFF / 2) * H; // 16384 A-pairs per sample
#define BN_SCALE 0.9999950000374997f

typedef _Float16 h2v __attribute__((ext_vector_type(2)));
union UH2 { uint32_t u; h2v h; };

__device__ __forceinline__ float fdot2u(uint32_t a, uint32_t b, float c) {
    UH2 x, y; x.u = a; y.u = b;
    return __builtin_amdgcn_fdot2(x.h, y.h, c, false);
}
__device__ __forceinline__ uint32_t packh2(float a, float b) {
    UH2 u; u.h = h2v{(_Float16)a, (_Float16)b}; return u.u;
}
__device__ __forceinline__ float gelu_exact(float x) {
    return 0.5f * x * (1.0f + erff(x * 0.70710678118654752f));
}

// ---------------------------------------------------------------------------
// Pack all vf weights to f16 pair layouts (one-time).
//  w0p[i2*HFF+j] = (w0[2*i2][j], w0[2*i2+1][j])              i2 < H/2
//  w1p/w2p same with i2 < HFF/2
//  wq[q*42 + r]: q = p*128+h (p = e-pair, h). r<21 -> e=2p d-pair r;
//                r>=21 -> e=2p+1 d-pair r-21
//  b3p[h*21+j] = (b3[h*42+2j], b3[h*42+2j+1])
// ---------------------------------------------------------------------------
__global__ void pack_kernel(const float* __restrict__ w0, const float* __restrict__ w1,
                            const float* __restrict__ w2, const float* __restrict__ w3,
                            const float* __restrict__ b3,
                            uint32_t* __restrict__ w0p, uint32_t* __restrict__ w1p,
                            uint32_t* __restrict__ w2p, uint32_t* __restrict__ wq,
                            uint32_t* __restrict__ b3p) {
    int idx = blockIdx.x * 256 + threadIdx.x;
    if (idx < (H / 2) * HFF) {
        int p = idx / HFF, j = idx % HFF;
        w0p[idx] = packh2(w0[(2 * p) * HFF + j], w0[(2 * p + 1) * HFF + j]);
    }
    if (idx < (HFF / 2) * HFF) {
        int p = idx / HFF, j = idx % HFF;
        w1p[idx] = packh2(w1[(2 * p) * HFF + j], w1[(2 * p + 1) * HFF + j]);
        w2p[idx] = packh2(w2[(2 * p) * HFF + j], w2[(2 * p + 1) * HFF + j]);
    }
    if (idx < H * DP) {
        int hh = idx / DP, j = idx % DP;
        b3p[idx] = packh2(b3[hh * D + 2 * j], b3[hh * D + 2 * j + 1]);
    }
    if (idx < QN * 42) {
        int qi = idx / 42, r = idx % 42;
        int p = qi >> 7, hh = qi & 127;
        int e = 2 * p + (r >= 21 ? 1 : 0);
        int j = (r >= 21) ? r - 21 : r;
        wq[idx] = packh2(w3[e * (H * D) + hh * D + 2 * j],
                         w3[e * (H * D) + hh * D + 2 * j + 1]);
    }
}

// ---------------------------------------------------------------------------
// Encoder (z0), dxdt f16 pairs, dt.  One block per sample, 128 threads.
// ---------------------------------------------------------------------------
__global__ void prep_kernel(const float* __restrict__ path, const float* __restrict__ ts,
                            const float* __restrict__ ew1, const float* __restrict__ eb1,
                            const float* __restrict__ eg1, const float* __restrict__ ebe1,
                            const float* __restrict__ ew2, const float* __restrict__ eb2,
                            const float* __restrict__ eg2, const float* __restrict__ ebe2,
                            float* __restrict__ zbuf, uint32_t* __restrict__ dxdtp,
                            float* __restrict__ dtb) {
    __shared__ float x0[D], hb[H];
    int b = blockIdx.x, tid = threadIdx.x;
    if (tid < D) x0[tid] = path[b * S * D + tid];
    __syncthreads();
    {
        float acc = eb1[tid];
        for (int d = 0; d < D; ++d) acc += x0[d] * ew1[d * H + tid];
        hb[tid] = gelu_exact(acc * (eg1[tid] * BN_SCALE) + ebe1[tid]);
    }
    __syncthreads();
    {
        float acc = eb2[tid];
        for (int i = 0; i < H; ++i) acc += hb[i] * ew2[i * H + tid];
        zbuf[b * H + tid] = acc * (eg2[tid] * BN_SCALE) + ebe2[tid];
    }
    for (int idx = tid; idx < NSTEP * DP; idx += 128) {
        int s = idx / DP, j = idx % DP;
        float dtv = ts[s + 1] - ts[s];
        int base = b * S * D + s * D + 2 * j;
        float v0 = (path[base + D] - path[base]) / dtv;
        float v1 = (path[base + D + 1] - path[base + 1]) / dtv;
        dxdtp[(s * B + b) * DP + j] = packh2(v0, v1);
    }
    if (b == 0 && tid < NSTEP) dtb[tid] = ts[tid + 1] - ts[tid];
}

// ---------------------------------------------------------------------------
// Fused per-step kernel.
//  blocks [0, eval_blocks)           : RK4 step s for sample b = blockIdx.x,
//                                      reading A from Ab_rd, z in zbuf.
//  blocks [eval_blocks, +512)        : compute A for step s+1 into Ab_wr.
// Double-buffered A so the halves never race.
// ---------------------------------------------------------------------------
__global__ void __launch_bounds__(256) step_kernel(
    const uint32_t* __restrict__ w0p, const uint32_t* __restrict__ w1p,
    const uint32_t* __restrict__ w2p, const uint32_t* __restrict__ wq,
    const uint32_t* __restrict__ b3p, const uint32_t* __restrict__ dxdtp,
    const float* __restrict__ vb0, const float* __restrict__ vg0, const float* __restrict__ vbe0,
    const float* __restrict__ vb1, const float* __restrict__ vg1, const float* __restrict__ vbe1,
    const float* __restrict__ vb2, const float* __restrict__ vg2, const float* __restrict__ vbe2,
    const float* __restrict__ dtb,
    const uint32_t* __restrict__ Ab_rd, uint32_t* __restrict__ Ab_wr,
    float* __restrict__ zbuf, int s, int eval_blocks) {
    int tid = threadIdx.x;

    if ((int)blockIdx.x >= eval_blocks) {
        // ----- A-part: A[b, q] for step s+1 -----
        int sa = s + 1;
        if (sa >= NSTEP) return;
        int idx = blockIdx.x - eval_blocks;     // 0..511
        int bc = idx >> 6;                      // 8 chunks of 32 samples
        int qt = idx & 63;                      // 64 q-tiles of 256
        int q = qt * 256 + tid;
        uint32_t wr[42];
        const uint32_t* wp = wq + (size_t)q * 42;
#pragma unroll
        for (int k = 0; k < 42; ++k) wr[k] = wp[k];
        int b0 = bc * 32;
        for (int b = b0; b < b0 + 32; ++b) {
            const uint32_t* dxp = dxdtp + (size_t)(sa * B + b) * DP;
            float a0 = 0.f, a1 = 0.f;
#pragma unroll
            for (int j = 0; j < DP; ++j) {
                uint32_t dx = dxp[j];
                a0 = fdot2u(wr[j], dx, a0);
                a1 = fdot2u(wr[21 + j], dx, a1);
            }
            Ab_wr[(size_t)b * QN + q] = packh2(a0, a1);
        }
        return;
    }

    // ----- eval part: one RK4 step for sample b -----
    __shared__ float zf[H], kcur[H], ksum[H], bd3v[H], l3part[H];
    __shared__ uint32_t zzp[H / 2], y0p[HFF / 2], y1p[HFF / 2], y2p[HFF / 2];
    int b = blockIdx.x;
    int h = tid & 127;
    float hstep = dtb[s];
    const uint32_t* dxp = dxdtp + (size_t)(s * B + b) * DP;
    if (tid < H) {
        zf[tid] = zbuf[b * H + tid];
        float acc = 0.f;
        const uint32_t* bp = b3p + tid * DP;
#pragma unroll
        for (int j = 0; j < DP; ++j) acc = fdot2u(bp[j], dxp[j], acc);
        bd3v[tid] = acc;
        ksum[tid] = 0.f;
    }
    float c0b = vb0[tid], c0g = vg0[tid] * BN_SCALE, c0e = vbe0[tid];
    float c1b = vb1[tid], c1g = vg1[tid] * BN_SCALE, c1e = vbe1[tid];
    float c2b = vb2[tid], c2g = vg2[tid] * BN_SCALE, c2e = vbe2[tid];
    const uint32_t* A32 = Ab_rd + (size_t)b * QN;
    const float cin[4] = {0.f, 0.5f, 0.5f, 1.f};
    const float wsm[4] = {1.f, 2.f, 2.f, 1.f};

    for (int r = 0; r < 4; ++r) {
        if (tid < H) {
            float zz = (r == 0) ? zf[tid] : zf[tid] + cin[r] * hstep * kcur[tid];
            ((_Float16*)zzp)[tid] = (_Float16)zz;
        }
        __syncthreads();
        // L0: 128 -> 256
        {
            float acc = c0b;
#pragma unroll 16
            for (int i = 0; i < H / 2; ++i) acc = fdot2u(w0p[i * HFF + tid], zzp[i], acc);
            ((_Float16*)y0p)[tid] = (_Float16)gelu_exact(acc * c0g + c0e);
        }
        __syncthreads();
        // L1: 256 -> 256
        {
            float acc = c1b;
#pragma unroll 16
            for (int i = 0; i < HFF / 2; ++i) acc = fdot2u(w1p[i * HFF + tid], y0p[i], acc);
            ((_Float16*)y1p)[tid] = (_Float16)gelu_exact(acc * c1g + c1e);
        }
        __syncthreads();
        // L2: 256 -> 256
        {
            float acc = c2b;
#pragma unroll 16
            for (int i = 0; i < HFF / 2; ++i) acc = fdot2u(w2p[i * HFF + tid], y1p[i], acc);
            ((_Float16*)y2p)[tid] = (_Float16)gelu_exact(acc * c2g + c2e);
        }
        __syncthreads();
        // L3: g[h] = bd3[h] + sum_p A[p,h] . y2[p]   (split over two half-waves)
        if (tid >= H) {
            float acc = 0.f;
#pragma unroll 16
            for (int p = 64; p < 128; ++p) acc = fdot2u(A32[p * H + h], y2p[p], acc);
            l3part[h] = acc;
        }
        __syncthreads();
        if (tid < H) {
            float acc = bd3v[tid] + l3part[tid];
#pragma unroll 16
            for (int p = 0; p < 64; ++p) acc = fdot2u(A32[p * H + tid], y2p[p], acc);
            kcur[tid] = acc;
            ksum[tid] += wsm[r] * acc;
        }
    }
    if (tid < H) zbuf[b * H + tid] = zf[tid] + (hstep * (1.f / 6.f)) * ksum[tid];
}

// ---------------------------------------------------------------------------
// attended = (zT@wv+bv)@wo+bo.  One block per sample, 128 threads.
// ---------------------------------------------------------------------------
__global__ void att_kernel(const float* __restrict__ zbuf,
                           const float* __restrict__ wv, const float* __restrict__ bv,
                           const float* __restrict__ wo, const float* __restrict__ bo,
                           float* __restrict__ att) {
    __shared__ float zl[H], v[H];
    int b = blockIdx.x, tid = threadIdx.x;
    zl[tid] = zbuf[b * H + tid];
    __syncthreads();
    {
        float acc = bv[tid];
#pragma unroll 8
        for (int i = 0; i < H; ++i) acc += zl[i] * wv[i * H + tid];
        v[tid] = acc;
    }
    __syncthreads();
    {
        float acc = bo[tid];
#pragma unroll 8
        for (int i = 0; i < H; ++i) acc += v[i] * wo[i * H + tid];
        att[b * H + tid] = acc;
    }
}

// ---------------------------------------------------------------------------
// Decoder: one single-wave block per (t, b).  grid = T*B = 5120.
// ---------------------------------------------------------------------------
__global__ void __launch_bounds__(64) dec_kernel(
    const float* __restrict__ att,
    const float* __restrict__ dw1, const float* __restrict__ db1,
    const float* __restrict__ dw2, const float* __restrict__ db2,
    const float* __restrict__ dw3, const float* __restrict__ db3,
    float* __restrict__ out) {
    int bid = blockIdx.x;
    int t = bid >> 8, b = bid & 255;
    int tid = threadIdx.x;
    __shared__ float al[H], h1l[64];
    al[tid] = att[b * H + tid];
    al[tid + 64] = att[b * H + tid + 64];
    __syncthreads();
    {
        float acc = db1[t * 64 + tid];
#pragma unroll 8
        for (int i = 0; i < H; ++i) acc += al[i] * dw1[t * H * 64 + i * 64 + tid];
        h1l[tid] = gelu_exact(acc);
    }
    __syncthreads();
    float v = 0.f;
    if (tid < 32) {
        float acc = db2[t * 32 + tid];
#pragma unroll 8
        for (int i = 0; i < 64; ++i) acc += h1l[i] * dw2[t * 64 * 32 + i * 32 + tid];
        v = gelu_exact(acc) * dw3[t * 32 + tid];
    }
#pragma unroll
    for (int off = 16; off >= 1; off >>= 1) v += __shfl_down(v, off, 64);
    if (tid == 0) out[b * T + t] = 1.f / (1.f + expf(-(v + db3[t])));
}

// ---------------------------------------------------------------------------
extern "C" void kernel_launch(void* const* d_in, const int* in_sizes, int n_in,
                              void* d_out, int out_size, void* d_ws, size_t ws_size,
                              hipStream_t stream) {
    const float* path = (const float*)d_in[0];
    const float* ts   = (const float*)d_in[1];
    const float* ew1  = (const float*)d_in[2];
    const float* eb1  = (const float*)d_in[3];
    const float* eg1  = (const float*)d_in[4];
    const float* ebe1 = (const float*)d_in[5];
    const float* ew2  = (const float*)d_in[6];
    const float* eb2  = (const float*)d_in[7];
    const float* eg2  = (const float*)d_in[8];
    const float* ebe2 = (const float*)d_in[9];
    const float* vw0  = (const float*)d_in[10];
    const float* vb0  = (const float*)d_in[11];
    const float* vg0  = (const float*)d_in[12];
    const float* vbe0 = (const float*)d_in[13];
    const float* vw1  = (const float*)d_in[14];
    const float* vb1  = (const float*)d_in[15];
    const float* vg1  = (const float*)d_in[16];
    const float* vbe1 = (const float*)d_in[17];
    const float* vw2  = (const float*)d_in[18];
    const float* vb2  = (const float*)d_in[19];
    const float* vg2  = (const float*)d_in[20];
    const float* vbe2 = (const float*)d_in[21];
    const float* vw3  = (const float*)d_in[22];
    const float* vb3  = (const float*)d_in[23];
    const float* wv   = (const float*)d_in[24];
    const float* bv   = (const float*)d_in[25];
    const float* wo   = (const float*)d_in[26];
    const float* bo   = (const float*)d_in[27];
    const float* dw1  = (const float*)d_in[28];
    const float* db1  = (const float*)d_in[29];
    const float* dw2  = (const float*)d_in[30];
    const float* db2  = (const float*)d_in[31];
    const float* dw3  = (const float*)d_in[32];
    const float* db3  = (const float*)d_in[33];

    // workspace layout (~37.6 MB; harness poison shows ws ~256 MiB)
    char* ws = (char*)d_ws;
    size_t off = 0;
    auto take = [&](size_t bytes) { char* p = ws + off; off += (bytes + 255) & ~(size_t)255; return p; };
    uint32_t* Ab0   = (uint32_t*)take((size_t)B * QN * 4);      // 16.78 MB
    uint32_t* Ab1   = (uint32_t*)take((size_t)B * QN * 4);      // 16.78 MB
    uint32_t* dxdtp = (uint32_t*)take((size_t)NSTEP * B * DP * 4);
    float*    dtb   = (float*)take(NSTEP * 4);
    float*    zbuf  = (float*)take((size_t)B * H * 4);
    float*    att   = (float*)take((size_t)B * H * 4);
    uint32_t* w0p   = (uint32_t*)take((size_t)(H / 2) * HFF * 4);
    uint32_t* w1p   = (uint32_t*)take((size_t)(HFF / 2) * HFF * 4);
    uint32_t* w2p   = (uint32_t*)take((size_t)(HFF / 2) * HFF * 4);
    uint32_t* wq    = (uint32_t*)take((size_t)QN * 42 * 4);
    uint32_t* b3p   = (uint32_t*)take((size_t)H * DP * 4);

    pack_kernel<<<(QN * 42 + 255) / 256, 256, 0, stream>>>(vw0, vw1, vw2, vw3, vb3,
                                                           w0p, w1p, w2p, wq, b3p);
    prep_kernel<<<B, 128, 0, stream>>>(path, ts, ew1, eb1, eg1, ebe1,
                                       ew2, eb2, eg2, ebe2, zbuf, dxdtp, dtb);
    // initial A for step 0 (a-part only)
    step_kernel<<<512, 256, 0, stream>>>(w0p, w1p, w2p, wq, b3p, dxdtp,
                                         vb0, vg0, vbe0, vb1, vg1, vbe1, vb2, vg2, vbe2,
                                         dtb, Ab1, Ab0, zbuf, -1, 0);
    for (int s = 0; s < NSTEP; ++s) {
        const uint32_t* rd = (s & 1) ? Ab1 : Ab0;
        uint32_t*       wr = (s & 1) ? Ab0 : Ab1;
        int grid = (s < NSTEP - 1) ? (B + 512) : B;
        step_kernel<<<grid, 256, 0, stream>>>(w0p, w1p, w2p, wq, b3p, dxdtp,
                                              vb0, vg0, vbe0, vb1, vg1, vbe1, vb2, vg2, vbe2,
                                              dtb, rd, wr, zbuf, s, B);
    }
    att_kernel<<<B, 128, 0, stream>>>(zbuf, wv, bv, wo, bo, att);
    dec_kernel<<<T * B, 64, 0, stream>>>(att, dw1, db1, dw2, db2, dw3, db3, (float*)d_out);
}